// Round 1
// baseline (493.978 us; speedup 1.0000x reference)
//
#include <hip/hip_runtime.h>
#include <hip/hip_bf16.h>
#include <stdint.h>

typedef __attribute__((ext_vector_type(8))) __bf16 bf16x8;
typedef __attribute__((ext_vector_type(4))) float f32x4;
typedef unsigned short u16;

#define N_NODES 51200
#define N_EDGES 819200
#define F_IN 400
#define H_DIM 256
#define C_OUT 2
#define N_GRAPHS 128
#define NODES_PER_GRAPH 400

__device__ __forceinline__ u16 f2bf(float f) {
  uint32_t u = __builtin_bit_cast(uint32_t, f);
  u = (u + 0x7fffu + ((u >> 16) & 1u)) >> 16;
  return (u16)u;
}
__device__ __forceinline__ float bf2f(u16 s) {
  uint32_t u = ((uint32_t)s) << 16;
  return __builtin_bit_cast(float, u);
}

// ---------------- degree histogram (counts[d] = in-degree) ----------------
__global__ void k_hist(const int* __restrict__ dst, int* __restrict__ counts, int E) {
  int e = blockIdx.x * 256 + threadIdx.x;
  if (e < E) atomicAdd(&counts[dst[e]], 1);
}

// ---------------- single-block exclusive scan -> csr_off, cursor ----------
__global__ __launch_bounds__(1024) void k_scan(const int* __restrict__ counts,
                                               int* __restrict__ off,
                                               int* __restrict__ cursor, int N) {
  __shared__ int sums[1024];
  int t = threadIdx.x;
  int per = (N + 1023) >> 10;            // 50
  int base = t * per;
  int s = 0;
  for (int i = 0; i < per; ++i) { int j = base + i; if (j < N) s += counts[j]; }
  sums[t] = s;
  __syncthreads();
  for (int d = 1; d < 1024; d <<= 1) {
    int v = (t >= d) ? sums[t - d] : 0;
    __syncthreads();
    sums[t] += v;
    __syncthreads();
  }
  int run = (t == 0) ? 0 : sums[t - 1];
  for (int i = 0; i < per; ++i) {
    int j = base + i;
    if (j < N) {
      off[j] = run; cursor[j] = run; run += counts[j];
      if (j == N - 1) off[N] = run;
    }
  }
}

// ---------------- dis = rsqrt(1 + deg) ------------------------------------
__global__ void k_dis(const int* __restrict__ counts, float* __restrict__ dis, int N) {
  int i = blockIdx.x * 256 + threadIdx.x;
  if (i < N) dis[i] = rsqrtf(1.0f + (float)counts[i]);
}

// ---------------- scatter edges into CSR (sorted by dst) ------------------
__global__ void k_scatter(const int* __restrict__ src, const int* __restrict__ dst,
                          int* __restrict__ cursor, int* __restrict__ csr_src, int E) {
  int e = blockIdx.x * 256 + threadIdx.x;
  if (e < E) {
    int d = dst[e];
    int p = atomicAdd(&cursor[d], 1);
    csr_src[p] = src[e];
  }
}

// ---------------- transpose weights to bf16 [n][k] ------------------------
__global__ void k_prepw(const float* __restrict__ W1, const float* __restrict__ W2,
                        u16* __restrict__ W1T, u16* __restrict__ W2T) {
  int id = blockIdx.x * 256 + threadIdx.x;
  if (id < F_IN * H_DIM) {
    int k = id >> 8, n = id & 255;
    W1T[n * F_IN + k] = f2bf(W1[id]);
  } else {
    int id2 = id - F_IN * H_DIM;
    if (id2 < H_DIM * H_DIM) {
      int k = id2 >> 8, n = id2 & 255;
      W2T[n * H_DIM + k] = f2bf(W2[id2]);
    }
  }
}

// ---------------- MFMA GEMM: C[M,256] = A[M,K] @ B[K,256] -----------------
// BT is bf16 [256][K] (pre-transposed). Block = 256 thr = 4 waves.
// Tile BM=64 x BN=256 (wave w does cols w*64..w*64+63), BK=32.
template <bool AF32>
__global__ __launch_bounds__(256) void k_mm(const void* __restrict__ Ap,
                                            const u16* __restrict__ BT,
                                            u16* __restrict__ C, int M, int K) {
  __shared__ __align__(16) u16 As[64][40];    // +8 pad: 80B row stride, 2-way banks
  __shared__ __align__(16) u16 Bs[256][40];
  int tid = threadIdx.x;
  int lane = tid & 63, wid = tid >> 6;
  int lr = lane & 15, lg = lane >> 4;
  int m0 = blockIdx.x * 64;
  f32x4 acc[4][4] = {};
  int nsteps = (K + 31) >> 5;
  for (int ks = 0; ks < nsteps; ++ks) {
    int k0 = ks << 5;
    // ---- stage A (64x32): each thread 8 elems
    {
      int row = tid >> 2;
      int seg = (tid & 3) << 3;
      int gk = k0 + seg;
      if (AF32) {
        const float* A = (const float*)Ap;
        const float* p = A + (size_t)(m0 + row) * K + gk;
        alignas(16) u16 u[8];
        if (gk + 8 <= K) {
#pragma unroll
          for (int j = 0; j < 8; ++j) u[j] = f2bf(p[j]);
        } else {
#pragma unroll
          for (int j = 0; j < 8; ++j) u[j] = (gk + j < K) ? f2bf(p[j]) : (u16)0;
        }
        *reinterpret_cast<uint4*>(&As[row][seg]) = *reinterpret_cast<const uint4*>(u);
      } else {
        const u16* A = (const u16*)Ap;
        const u16* p = A + (size_t)(m0 + row) * K + gk;
        if (gk + 8 <= K) {
          *reinterpret_cast<uint4*>(&As[row][seg]) = *reinterpret_cast<const uint4*>(p);
        } else {
          alignas(16) u16 u[8];
#pragma unroll
          for (int j = 0; j < 8; ++j) u[j] = (gk + j < K) ? p[j] : (u16)0;
          *reinterpret_cast<uint4*>(&As[row][seg]) = *reinterpret_cast<const uint4*>(u);
        }
      }
    }
    // ---- stage B (256 n-rows x 32 k): each thread one n row
    {
      int n = tid;
      const u16* p = BT + (size_t)n * K + k0;
      if (k0 + 32 <= K) {
#pragma unroll
        for (int j = 0; j < 4; ++j)
          *reinterpret_cast<uint4*>(&Bs[n][j * 8]) = reinterpret_cast<const uint4*>(p)[j];
      } else {
        alignas(16) u16 u[32];
#pragma unroll
        for (int j = 0; j < 32; ++j) u[j] = (k0 + j < K) ? p[j] : (u16)0;
#pragma unroll
        for (int j = 0; j < 4; ++j)
          *reinterpret_cast<uint4*>(&Bs[n][j * 8]) = reinterpret_cast<const uint4*>(u)[j];
      }
    }
    __syncthreads();
    bf16x8 af[4], bfr[4];
#pragma unroll
    for (int m = 0; m < 4; ++m)
      af[m] = *reinterpret_cast<const bf16x8*>(&As[m * 16 + lr][lg * 8]);
#pragma unroll
    for (int n = 0; n < 4; ++n)
      bfr[n] = *reinterpret_cast<const bf16x8*>(&Bs[wid * 64 + n * 16 + lr][lg * 8]);
#pragma unroll
    for (int m = 0; m < 4; ++m)
#pragma unroll
      for (int n = 0; n < 4; ++n)
        acc[m][n] = __builtin_amdgcn_mfma_f32_16x16x32_bf16(af[m], bfr[n], acc[m][n], 0, 0, 0);
    __syncthreads();
  }
  // ---- epilogue: D[row=(lg*4+r)][col=lr] per 16x16 frag
#pragma unroll
  for (int m = 0; m < 4; ++m)
#pragma unroll
    for (int n = 0; n < 4; ++n)
#pragma unroll
      for (int r = 0; r < 4; ++r) {
        int grow = m0 + m * 16 + lg * 4 + r;
        int gcol = wid * 64 + n * 16 + lr;
        C[(size_t)grow * H_DIM + gcol] = f2bf(acc[m][n][r]);
      }
}

// ---------------- aggregation: h[d] = relu(sum_e dis[s]dis[d] t[s] + dis[d]^2 t[d] + b)
// one wave per node, lane = 4 features
template <bool RELU>
__global__ __launch_bounds__(256) void k_agg(const u16* __restrict__ t,
                                             const int* __restrict__ off,
                                             const int* __restrict__ csr,
                                             const float* __restrict__ dis,
                                             const float* __restrict__ bias,
                                             u16* __restrict__ h, int N) {
  int wid = threadIdx.x >> 6, lane = threadIdx.x & 63;
  int d = blockIdx.x * 4 + wid;
  if (d >= N) return;
  int f0 = lane * 4;
  float dd = dis[d];
  float acc0, acc1, acc2, acc3;
  {
    ushort4 v = *reinterpret_cast<const ushort4*>(t + (size_t)d * H_DIM + f0);
    float w = dd * dd;
    acc0 = w * bf2f(v.x); acc1 = w * bf2f(v.y); acc2 = w * bf2f(v.z); acc3 = w * bf2f(v.w);
  }
  int e0 = off[d], e1 = off[d + 1];
  int e = e0;
  for (; e + 1 < e1; e += 2) {
    int s0 = csr[e], s1 = csr[e + 1];
    float w0 = dd * dis[s0], w1 = dd * dis[s1];
    ushort4 v0 = *reinterpret_cast<const ushort4*>(t + (size_t)s0 * H_DIM + f0);
    ushort4 v1 = *reinterpret_cast<const ushort4*>(t + (size_t)s1 * H_DIM + f0);
    acc0 += w0 * bf2f(v0.x) + w1 * bf2f(v1.x);
    acc1 += w0 * bf2f(v0.y) + w1 * bf2f(v1.y);
    acc2 += w0 * bf2f(v0.z) + w1 * bf2f(v1.z);
    acc3 += w0 * bf2f(v0.w) + w1 * bf2f(v1.w);
  }
  if (e < e1) {
    int s0 = csr[e];
    float w0 = dd * dis[s0];
    ushort4 v0 = *reinterpret_cast<const ushort4*>(t + (size_t)s0 * H_DIM + f0);
    acc0 += w0 * bf2f(v0.x); acc1 += w0 * bf2f(v0.y);
    acc2 += w0 * bf2f(v0.z); acc3 += w0 * bf2f(v0.w);
  }
  float4 bv = *reinterpret_cast<const float4*>(bias + f0);
  float r0 = acc0 + bv.x, r1 = acc1 + bv.y, r2 = acc2 + bv.z, r3 = acc3 + bv.w;
  if (RELU) {
    r0 = fmaxf(r0, 0.f); r1 = fmaxf(r1, 0.f); r2 = fmaxf(r2, 0.f); r3 = fmaxf(r3, 0.f);
  }
  ushort4 o;
  o.x = f2bf(r0); o.y = f2bf(r1); o.z = f2bf(r2); o.w = f2bf(r3);
  *reinterpret_cast<ushort4*>(h + (size_t)d * H_DIM + f0) = o;
}

// ---------------- layer 3 matmul: t3[N,2] = h2[N,256] @ W3[256,2] ---------
__global__ __launch_bounds__(256) void k_mm3(const u16* __restrict__ h2,
                                             const float* __restrict__ W3,
                                             float* __restrict__ t3, int N) {
  int wid = threadIdx.x >> 6, lane = threadIdx.x & 63;
  int d = blockIdx.x * 4 + wid;
  if (d >= N) return;
  int f0 = lane * 4;
  ushort4 v = *reinterpret_cast<const ushort4*>(h2 + (size_t)d * H_DIM + f0);
  float a0 = 0.f, a1 = 0.f, f;
  f = bf2f(v.x); a0 += f * W3[(f0 + 0) * 2]; a1 += f * W3[(f0 + 0) * 2 + 1];
  f = bf2f(v.y); a0 += f * W3[(f0 + 1) * 2]; a1 += f * W3[(f0 + 1) * 2 + 1];
  f = bf2f(v.z); a0 += f * W3[(f0 + 2) * 2]; a1 += f * W3[(f0 + 2) * 2 + 1];
  f = bf2f(v.w); a0 += f * W3[(f0 + 3) * 2]; a1 += f * W3[(f0 + 3) * 2 + 1];
#pragma unroll
  for (int o = 32; o; o >>= 1) { a0 += __shfl_xor(a0, o); a1 += __shfl_xor(a1, o); }
  if (lane == 0) { t3[d * 2] = a0; t3[d * 2 + 1] = a1; }
}

// ---------------- layer 3 aggregation (2 features, no relu) ---------------
__global__ void k_agg3(const float* __restrict__ t3, const int* __restrict__ off,
                       const int* __restrict__ csr, const float* __restrict__ dis,
                       const float* __restrict__ b3, float* __restrict__ h3, int N) {
  int d = blockIdx.x * 256 + threadIdx.x;
  if (d >= N) return;
  float dd = dis[d];
  float a0 = dd * dd * t3[d * 2], a1 = dd * dd * t3[d * 2 + 1];
  int e1 = off[d + 1];
  for (int e = off[d]; e < e1; ++e) {
    int s = csr[e];
    float w = dd * dis[s];
    a0 += w * t3[s * 2]; a1 += w * t3[s * 2 + 1];
  }
  h3[d * 2] = a0 + b3[0];
  h3[d * 2 + 1] = a1 + b3[1];
}

// ---------------- mean pool over 400 nodes per graph ----------------------
__global__ __launch_bounds__(256) void k_pool(const float* __restrict__ h3,
                                              float* __restrict__ out, int G) {
  int wid = threadIdx.x >> 6, lane = threadIdx.x & 63;
  int g = blockIdx.x * 4 + wid;
  if (g >= G) return;
  float a0 = 0.f, a1 = 0.f;
  for (int i = lane; i < NODES_PER_GRAPH; i += 64) {
    int n = g * NODES_PER_GRAPH + i;
    a0 += h3[n * 2]; a1 += h3[n * 2 + 1];
  }
#pragma unroll
  for (int o = 32; o; o >>= 1) { a0 += __shfl_xor(a0, o); a1 += __shfl_xor(a1, o); }
  if (lane == 0) {
    out[g * 2] = a0 * (1.0f / NODES_PER_GRAPH);
    out[g * 2 + 1] = a1 * (1.0f / NODES_PER_GRAPH);
  }
}

extern "C" void kernel_launch(void* const* d_in, const int* in_sizes, int n_in,
                              void* d_out, int out_size, void* d_ws, size_t ws_size,
                              hipStream_t stream) {
  const float* x  = (const float*)d_in[0];
  const int*   ei = (const int*)d_in[1];
  const float* W1 = (const float*)d_in[2];
  const float* b1 = (const float*)d_in[3];
  const float* W2 = (const float*)d_in[4];
  const float* b2 = (const float*)d_in[5];
  const float* W3 = (const float*)d_in[6];
  const float* b3 = (const float*)d_in[7];
  float* out = (float*)d_out;
  const int N = N_NODES, E = N_EDGES;
  const int* src = ei;
  const int* dst = ei + E;

  char* ws = (char*)d_ws;
  size_t o = 0;
  auto alloc = [&](size_t bytes) -> void* {
    void* p = ws + o;
    o += (bytes + 255) & ~(size_t)255;
    return p;
  };
  u16* tA     = (u16*)alloc((size_t)N * H_DIM * 2);
  u16* tB     = (u16*)alloc((size_t)N * H_DIM * 2);
  u16* W1T    = (u16*)alloc((size_t)H_DIM * F_IN * 2);
  u16* W2T    = (u16*)alloc((size_t)H_DIM * H_DIM * 2);
  float* dis  = (float*)alloc((size_t)N * 4);
  int* counts = (int*)alloc((size_t)N * 4);
  int* cursor = (int*)alloc((size_t)N * 4);
  int* csroff = (int*)alloc((size_t)(N + 1) * 4);
  int* csr    = (int*)alloc((size_t)E * 4);
  float* t3   = (float*)alloc((size_t)N * 2 * 4);
  float* h3   = (float*)alloc((size_t)N * 2 * 4);

  hipMemsetAsync(counts, 0, (size_t)N * 4, stream);
  k_hist<<<(E + 255) / 256, 256, 0, stream>>>(dst, counts, E);
  k_scan<<<1, 1024, 0, stream>>>(counts, csroff, cursor, N);
  k_dis<<<(N + 255) / 256, 256, 0, stream>>>(counts, dis, N);
  k_scatter<<<(E + 255) / 256, 256, 0, stream>>>(src, dst, cursor, csr, E);
  k_prepw<<<(F_IN * H_DIM + H_DIM * H_DIM + 255) / 256, 256, 0, stream>>>(W1, W2, W1T, W2T);

  // layer 1
  k_mm<true><<<N / 64, 256, 0, stream>>>(x, W1T, tA, N, F_IN);
  k_agg<true><<<N / 4, 256, 0, stream>>>(tA, csroff, csr, dis, b1, tB, N);
  // layer 2
  k_mm<false><<<N / 64, 256, 0, stream>>>(tB, W2T, tA, N, H_DIM);
  k_agg<true><<<N / 4, 256, 0, stream>>>(tA, csroff, csr, dis, b2, tB, N);
  // layer 3
  k_mm3<<<N / 4, 256, 0, stream>>>(tB, W3, t3, N);
  k_agg3<<<(N + 255) / 256, 256, 0, stream>>>(t3, csroff, csr, dis, b3, h3, N);
  k_pool<<<(N_GRAPHS + 3) / 4, 256, 0, stream>>>(h3, out, N_GRAPHS);
}

// Round 2
// 379.599 us; speedup vs baseline: 1.3013x; 1.3013x over previous
//
#include <hip/hip_runtime.h>
#include <hip/hip_bf16.h>
#include <stdint.h>

typedef __attribute__((ext_vector_type(8))) __bf16 bf16x8;
typedef __attribute__((ext_vector_type(4))) float f32x4;
typedef unsigned short u16;

#define N_NODES 51200
#define N_EDGES 819200
#define F_IN 400
#define H_DIM 256
#define C_OUT 2
#define N_GRAPHS 128
#define NODES_PER_GRAPH 400
#define NB_SCAN (N_NODES / 256)   // 200 blocks

__device__ __forceinline__ u16 f2bf(float f) {
  uint32_t u = __builtin_bit_cast(uint32_t, f);
  u = (u + 0x7fffu + ((u >> 16) & 1u)) >> 16;
  return (u16)u;
}
__device__ __forceinline__ float bf2f(u16 s) {
  uint32_t u = ((uint32_t)s) << 16;
  return __builtin_bit_cast(float, u);
}

// ---------------- degree histogram (counts[d] = in-degree) ----------------
__global__ void k_hist(const int* __restrict__ dst, int* __restrict__ counts, int E) {
  int e = blockIdx.x * 256 + threadIdx.x;
  if (e < E) atomicAdd(&counts[dst[e]], 1);
}

// ---------------- hierarchical scan: phase 1, per-block sums --------------
__global__ __launch_bounds__(256) void k_reduce(const int* __restrict__ counts,
                                                int* __restrict__ bsum) {
  int i = blockIdx.x * 256 + threadIdx.x;
  int v = counts[i];
#pragma unroll
  for (int o = 32; o; o >>= 1) v += __shfl_xor(v, o);
  __shared__ int wsum[4];
  if ((threadIdx.x & 63) == 0) wsum[threadIdx.x >> 6] = v;
  __syncthreads();
  if (threadIdx.x == 0) bsum[blockIdx.x] = wsum[0] + wsum[1] + wsum[2] + wsum[3];
}

// ---------------- phase 2: scan the 200 block sums (one small block) ------
__global__ __launch_bounds__(256) void k_scantop(const int* __restrict__ bsum,
                                                 int* __restrict__ boff,
                                                 int* __restrict__ off_last) {
  __shared__ int s[256];
  int t = threadIdx.x;
  int v = (t < NB_SCAN) ? bsum[t] : 0;
  s[t] = v;
  __syncthreads();
  for (int d = 1; d < 256; d <<= 1) {
    int u = (t >= d) ? s[t - d] : 0;
    __syncthreads();
    s[t] += u;
    __syncthreads();
  }
  if (t < NB_SCAN) boff[t] = s[t] - v;   // exclusive prefix of block sums
  if (t == 0) *off_last = N_EDGES;       // off[N] = total edges
}

// ---------------- phase 3: local scan + block offset; also dis ------------
__global__ __launch_bounds__(256) void k_scanlocal(const int* __restrict__ counts,
                                                   const int* __restrict__ boff,
                                                   int* __restrict__ off,
                                                   int* __restrict__ cursor,
                                                   float* __restrict__ dis) {
  __shared__ int s[256];
  int t = threadIdx.x;
  int i = blockIdx.x * 256 + t;
  int v = counts[i];
  s[t] = v;
  __syncthreads();
  for (int d = 1; d < 256; d <<= 1) {
    int u = (t >= d) ? s[t - d] : 0;
    __syncthreads();
    s[t] += u;
    __syncthreads();
  }
  int ex = boff[blockIdx.x] + s[t] - v;
  off[i] = ex;
  cursor[i] = ex;
  dis[i] = rsqrtf(1.0f + (float)v);
}

// ---------------- scatter edges into CSR (sorted by dst) ------------------
__global__ void k_scatter(const int* __restrict__ src, const int* __restrict__ dst,
                          int* __restrict__ cursor, int* __restrict__ csr_src, int E) {
  int e = blockIdx.x * 256 + threadIdx.x;
  if (e < E) {
    int d = dst[e];
    int p = atomicAdd(&cursor[d], 1);
    csr_src[p] = src[e];
  }
}

// ---------------- transpose weights to bf16 [n][k] ------------------------
__global__ void k_prepw(const float* __restrict__ W1, const float* __restrict__ W2,
                        u16* __restrict__ W1T, u16* __restrict__ W2T) {
  int id = blockIdx.x * 256 + threadIdx.x;
  if (id < F_IN * H_DIM) {
    int k = id >> 8, n = id & 255;
    W1T[n * F_IN + k] = f2bf(W1[id]);
  } else {
    int id2 = id - F_IN * H_DIM;
    if (id2 < H_DIM * H_DIM) {
      int k = id2 >> 8, n = id2 & 255;
      W2T[n * H_DIM + k] = f2bf(W2[id2]);
    }
  }
}

// ---------------- MFMA GEMM: C[M,256] = A[M,K] @ B[K,256] -----------------
// BT is bf16 [256][K] (pre-transposed). Block = 256 thr = 4 waves.
// Tile BM=64 x BN=256 (wave w does cols w*64..w*64+63), BK=32.
template <bool AF32>
__global__ __launch_bounds__(256) void k_mm(const void* __restrict__ Ap,
                                            const u16* __restrict__ BT,
                                            u16* __restrict__ C, int M, int K) {
  __shared__ __align__(16) u16 As[64][40];    // +8 pad: 80B row stride, 2-way banks
  __shared__ __align__(16) u16 Bs[256][40];
  int tid = threadIdx.x;
  int lane = tid & 63, wid = tid >> 6;
  int lr = lane & 15, lg = lane >> 4;
  int m0 = blockIdx.x * 64;
  f32x4 acc[4][4] = {};
  int nsteps = (K + 31) >> 5;
  for (int ks = 0; ks < nsteps; ++ks) {
    int k0 = ks << 5;
    // ---- stage A (64x32): each thread 8 elems
    {
      int row = tid >> 2;
      int seg = (tid & 3) << 3;
      int gk = k0 + seg;
      if (AF32) {
        const float* A = (const float*)Ap;
        const float* p = A + (size_t)(m0 + row) * K + gk;
        alignas(16) u16 u[8];
        if (gk + 8 <= K) {
#pragma unroll
          for (int j = 0; j < 8; ++j) u[j] = f2bf(p[j]);
        } else {
#pragma unroll
          for (int j = 0; j < 8; ++j) u[j] = (gk + j < K) ? f2bf(p[j]) : (u16)0;
        }
        *reinterpret_cast<uint4*>(&As[row][seg]) = *reinterpret_cast<const uint4*>(u);
      } else {
        const u16* A = (const u16*)Ap;
        const u16* p = A + (size_t)(m0 + row) * K + gk;
        if (gk + 8 <= K) {
          *reinterpret_cast<uint4*>(&As[row][seg]) = *reinterpret_cast<const uint4*>(p);
        } else {
          alignas(16) u16 u[8];
#pragma unroll
          for (int j = 0; j < 8; ++j) u[j] = (gk + j < K) ? p[j] : (u16)0;
          *reinterpret_cast<uint4*>(&As[row][seg]) = *reinterpret_cast<const uint4*>(u);
        }
      }
    }
    // ---- stage B (256 n-rows x 32 k): each thread one n row
    {
      int n = tid;
      const u16* p = BT + (size_t)n * K + k0;
      if (k0 + 32 <= K) {
#pragma unroll
        for (int j = 0; j < 4; ++j)
          *reinterpret_cast<uint4*>(&Bs[n][j * 8]) = reinterpret_cast<const uint4*>(p)[j];
      } else {
        alignas(16) u16 u[32];
#pragma unroll
        for (int j = 0; j < 32; ++j) u[j] = (k0 + j < K) ? p[j] : (u16)0;
#pragma unroll
        for (int j = 0; j < 4; ++j)
          *reinterpret_cast<uint4*>(&Bs[n][j * 8]) = reinterpret_cast<const uint4*>(u)[j];
      }
    }
    __syncthreads();
    bf16x8 af[4], bfr[4];
#pragma unroll
    for (int m = 0; m < 4; ++m)
      af[m] = *reinterpret_cast<const bf16x8*>(&As[m * 16 + lr][lg * 8]);
#pragma unroll
    for (int n = 0; n < 4; ++n)
      bfr[n] = *reinterpret_cast<const bf16x8*>(&Bs[wid * 64 + n * 16 + lr][lg * 8]);
#pragma unroll
    for (int m = 0; m < 4; ++m)
#pragma unroll
      for (int n = 0; n < 4; ++n)
        acc[m][n] = __builtin_amdgcn_mfma_f32_16x16x32_bf16(af[m], bfr[n], acc[m][n], 0, 0, 0);
    __syncthreads();
  }
  // ---- epilogue: D[row=(lg*4+r)][col=lr] per 16x16 frag
#pragma unroll
  for (int m = 0; m < 4; ++m)
#pragma unroll
    for (int n = 0; n < 4; ++n)
#pragma unroll
      for (int r = 0; r < 4; ++r) {
        int grow = m0 + m * 16 + lg * 4 + r;
        int gcol = wid * 64 + n * 16 + lr;
        C[(size_t)grow * H_DIM + gcol] = f2bf(acc[m][n][r]);
      }
}

// ---------------- aggregation: h[d] = relu(sum_e dis[s]dis[d] t[s] + dis[d]^2 t[d] + b)
// one wave per node, lane = 4 features
template <bool RELU>
__global__ __launch_bounds__(256) void k_agg(const u16* __restrict__ t,
                                             const int* __restrict__ off,
                                             const int* __restrict__ csr,
                                             const float* __restrict__ dis,
                                             const float* __restrict__ bias,
                                             u16* __restrict__ h, int N) {
  int wid = threadIdx.x >> 6, lane = threadIdx.x & 63;
  int d = blockIdx.x * 4 + wid;
  if (d >= N) return;
  int f0 = lane * 4;
  float dd = dis[d];
  float acc0, acc1, acc2, acc3;
  {
    ushort4 v = *reinterpret_cast<const ushort4*>(t + (size_t)d * H_DIM + f0);
    float w = dd * dd;
    acc0 = w * bf2f(v.x); acc1 = w * bf2f(v.y); acc2 = w * bf2f(v.z); acc3 = w * bf2f(v.w);
  }
  int e0 = off[d], e1 = off[d + 1];
  int e = e0;
  for (; e + 1 < e1; e += 2) {
    int s0 = csr[e], s1 = csr[e + 1];
    float w0 = dd * dis[s0], w1 = dd * dis[s1];
    ushort4 v0 = *reinterpret_cast<const ushort4*>(t + (size_t)s0 * H_DIM + f0);
    ushort4 v1 = *reinterpret_cast<const ushort4*>(t + (size_t)s1 * H_DIM + f0);
    acc0 += w0 * bf2f(v0.x) + w1 * bf2f(v1.x);
    acc1 += w0 * bf2f(v0.y) + w1 * bf2f(v1.y);
    acc2 += w0 * bf2f(v0.z) + w1 * bf2f(v1.z);
    acc3 += w0 * bf2f(v0.w) + w1 * bf2f(v1.w);
  }
  if (e < e1) {
    int s0 = csr[e];
    float w0 = dd * dis[s0];
    ushort4 v0 = *reinterpret_cast<const ushort4*>(t + (size_t)s0 * H_DIM + f0);
    acc0 += w0 * bf2f(v0.x); acc1 += w0 * bf2f(v0.y);
    acc2 += w0 * bf2f(v0.z); acc3 += w0 * bf2f(v0.w);
  }
  float4 bv = *reinterpret_cast<const float4*>(bias + f0);
  float r0 = acc0 + bv.x, r1 = acc1 + bv.y, r2 = acc2 + bv.z, r3 = acc3 + bv.w;
  if (RELU) {
    r0 = fmaxf(r0, 0.f); r1 = fmaxf(r1, 0.f); r2 = fmaxf(r2, 0.f); r3 = fmaxf(r3, 0.f);
  }
  ushort4 o;
  o.x = f2bf(r0); o.y = f2bf(r1); o.z = f2bf(r2); o.w = f2bf(r3);
  *reinterpret_cast<ushort4*>(h + (size_t)d * H_DIM + f0) = o;
}

// ---------------- layer 3 matmul: t3[N,2] = h2[N,256] @ W3[256,2] ---------
__global__ __launch_bounds__(256) void k_mm3(const u16* __restrict__ h2,
                                             const float* __restrict__ W3,
                                             float* __restrict__ t3, int N) {
  int wid = threadIdx.x >> 6, lane = threadIdx.x & 63;
  int d = blockIdx.x * 4 + wid;
  if (d >= N) return;
  int f0 = lane * 4;
  ushort4 v = *reinterpret_cast<const ushort4*>(h2 + (size_t)d * H_DIM + f0);
  float a0 = 0.f, a1 = 0.f, f;
  f = bf2f(v.x); a0 += f * W3[(f0 + 0) * 2]; a1 += f * W3[(f0 + 0) * 2 + 1];
  f = bf2f(v.y); a0 += f * W3[(f0 + 1) * 2]; a1 += f * W3[(f0 + 1) * 2 + 1];
  f = bf2f(v.z); a0 += f * W3[(f0 + 2) * 2]; a1 += f * W3[(f0 + 2) * 2 + 1];
  f = bf2f(v.w); a0 += f * W3[(f0 + 3) * 2]; a1 += f * W3[(f0 + 3) * 2 + 1];
#pragma unroll
  for (int o = 32; o; o >>= 1) { a0 += __shfl_xor(a0, o); a1 += __shfl_xor(a1, o); }
  if (lane == 0) { t3[d * 2] = a0; t3[d * 2 + 1] = a1; }
}

// ---------------- layer 3 aggregation (2 features, no relu) ---------------
__global__ void k_agg3(const float* __restrict__ t3, const int* __restrict__ off,
                       const int* __restrict__ csr, const float* __restrict__ dis,
                       const float* __restrict__ b3, float* __restrict__ h3, int N) {
  int d = blockIdx.x * 256 + threadIdx.x;
  if (d >= N) return;
  float dd = dis[d];
  float a0 = dd * dd * t3[d * 2], a1 = dd * dd * t3[d * 2 + 1];
  int e1 = off[d + 1];
  for (int e = off[d]; e < e1; ++e) {
    int s = csr[e];
    float w = dd * dis[s];
    a0 += w * t3[s * 2]; a1 += w * t3[s * 2 + 1];
  }
  h3[d * 2] = a0 + b3[0];
  h3[d * 2 + 1] = a1 + b3[1];
}

// ---------------- mean pool over 400 nodes per graph ----------------------
__global__ __launch_bounds__(256) void k_pool(const float* __restrict__ h3,
                                              float* __restrict__ out, int G) {
  int wid = threadIdx.x >> 6, lane = threadIdx.x & 63;
  int g = blockIdx.x * 4 + wid;
  if (g >= G) return;
  float a0 = 0.f, a1 = 0.f;
  for (int i = lane; i < NODES_PER_GRAPH; i += 64) {
    int n = g * NODES_PER_GRAPH + i;
    a0 += h3[n * 2]; a1 += h3[n * 2 + 1];
  }
#pragma unroll
  for (int o = 32; o; o >>= 1) { a0 += __shfl_xor(a0, o); a1 += __shfl_xor(a1, o); }
  if (lane == 0) {
    out[g * 2] = a0 * (1.0f / NODES_PER_GRAPH);
    out[g * 2 + 1] = a1 * (1.0f / NODES_PER_GRAPH);
  }
}

extern "C" void kernel_launch(void* const* d_in, const int* in_sizes, int n_in,
                              void* d_out, int out_size, void* d_ws, size_t ws_size,
                              hipStream_t stream) {
  const float* x  = (const float*)d_in[0];
  const int*   ei = (const int*)d_in[1];
  const float* W1 = (const float*)d_in[2];
  const float* b1 = (const float*)d_in[3];
  const float* W2 = (const float*)d_in[4];
  const float* b2 = (const float*)d_in[5];
  const float* W3 = (const float*)d_in[6];
  const float* b3 = (const float*)d_in[7];
  float* out = (float*)d_out;
  const int N = N_NODES, E = N_EDGES;
  const int* src = ei;
  const int* dst = ei + E;

  char* ws = (char*)d_ws;
  size_t o = 0;
  auto alloc = [&](size_t bytes) -> void* {
    void* p = ws + o;
    o += (bytes + 255) & ~(size_t)255;
    return p;
  };
  u16* tA     = (u16*)alloc((size_t)N * H_DIM * 2);
  u16* tB     = (u16*)alloc((size_t)N * H_DIM * 2);
  u16* W1T    = (u16*)alloc((size_t)H_DIM * F_IN * 2);
  u16* W2T    = (u16*)alloc((size_t)H_DIM * H_DIM * 2);
  float* dis  = (float*)alloc((size_t)N * 4);
  int* counts = (int*)alloc((size_t)N * 4);
  int* cursor = (int*)alloc((size_t)N * 4);
  int* csroff = (int*)alloc((size_t)(N + 1) * 4);
  int* csr    = (int*)alloc((size_t)E * 4);
  float* t3   = (float*)alloc((size_t)N * 2 * 4);
  float* h3   = (float*)alloc((size_t)N * 2 * 4);
  int* bsum   = (int*)alloc((size_t)NB_SCAN * 4);
  int* boff   = (int*)alloc((size_t)NB_SCAN * 4);

  hipMemsetAsync(counts, 0, (size_t)N * 4, stream);
  k_hist<<<(E + 255) / 256, 256, 0, stream>>>(dst, counts, E);
  k_reduce<<<NB_SCAN, 256, 0, stream>>>(counts, bsum);
  k_scantop<<<1, 256, 0, stream>>>(bsum, boff, csroff + N);
  k_scanlocal<<<NB_SCAN, 256, 0, stream>>>(counts, boff, csroff, cursor, dis);
  k_scatter<<<(E + 255) / 256, 256, 0, stream>>>(src, dst, cursor, csr, E);
  k_prepw<<<(F_IN * H_DIM + H_DIM * H_DIM + 255) / 256, 256, 0, stream>>>(W1, W2, W1T, W2T);

  // layer 1
  k_mm<true><<<N / 64, 256, 0, stream>>>(x, W1T, tA, N, F_IN);
  k_agg<true><<<N / 4, 256, 0, stream>>>(tA, csroff, csr, dis, b1, tB, N);
  // layer 2
  k_mm<false><<<N / 64, 256, 0, stream>>>(tB, W2T, tA, N, H_DIM);
  k_agg<true><<<N / 4, 256, 0, stream>>>(tA, csroff, csr, dis, b2, tB, N);
  // layer 3
  k_mm3<<<N / 4, 256, 0, stream>>>(tB, W3, t3, N);
  k_agg3<<<(N + 255) / 256, 256, 0, stream>>>(t3, csroff, csr, dis, b3, h3, N);
  k_pool<<<(N_GRAPHS + 3) / 4, 256, 0, stream>>>(h3, out, N_GRAPHS);
}

// Round 3
// 325.482 us; speedup vs baseline: 1.5177x; 1.1663x over previous
//
#include <hip/hip_runtime.h>
#include <hip/hip_bf16.h>
#include <stdint.h>

typedef __attribute__((ext_vector_type(8))) __bf16 bf16x8;
typedef __attribute__((ext_vector_type(4))) float f32x4;
typedef unsigned short u16;

#define N_NODES 51200
#define N_EDGES 819200
#define F_IN 400
#define H_DIM 256
#define C_OUT 2
#define N_GRAPHS 128
#define NODES_PER_GRAPH 400
#define NB_SCAN (N_NODES / 256)   // 200 blocks

__device__ __forceinline__ u16 f2bf(float f) {
  uint32_t u = __builtin_bit_cast(uint32_t, f);
  u = (u + 0x7fffu + ((u >> 16) & 1u)) >> 16;
  return (u16)u;
}
__device__ __forceinline__ float bf2f(u16 s) {
  uint32_t u = ((uint32_t)s) << 16;
  return __builtin_bit_cast(float, u);
}

// ---------------- degree histogram (counts[d] = in-degree) ----------------
__global__ void k_hist(const int* __restrict__ dst, int* __restrict__ counts, int E) {
  int e = blockIdx.x * 256 + threadIdx.x;
  if (e < E) atomicAdd(&counts[dst[e]], 1);
}

// ---------------- hierarchical scan: phase 1, per-block sums --------------
__global__ __launch_bounds__(256) void k_reduce(const int* __restrict__ counts,
                                                int* __restrict__ bsum) {
  int i = blockIdx.x * 256 + threadIdx.x;
  int v = counts[i];
#pragma unroll
  for (int o = 32; o; o >>= 1) v += __shfl_xor(v, o);
  __shared__ int wsum[4];
  if ((threadIdx.x & 63) == 0) wsum[threadIdx.x >> 6] = v;
  __syncthreads();
  if (threadIdx.x == 0) bsum[blockIdx.x] = wsum[0] + wsum[1] + wsum[2] + wsum[3];
}

// ---------------- phase 2: scan the 200 block sums (one small block) ------
__global__ __launch_bounds__(256) void k_scantop(const int* __restrict__ bsum,
                                                 int* __restrict__ boff,
                                                 int* __restrict__ off_last) {
  __shared__ int s[256];
  int t = threadIdx.x;
  int v = (t < NB_SCAN) ? bsum[t] : 0;
  s[t] = v;
  __syncthreads();
  for (int d = 1; d < 256; d <<= 1) {
    int u = (t >= d) ? s[t - d] : 0;
    __syncthreads();
    s[t] += u;
    __syncthreads();
  }
  if (t < NB_SCAN) boff[t] = s[t] - v;   // exclusive prefix of block sums
  if (t == 0) *off_last = N_EDGES;       // off[N] = total edges
}

// ---------------- phase 3: local scan + block offset; also dis ------------
__global__ __launch_bounds__(256) void k_scanlocal(const int* __restrict__ counts,
                                                   const int* __restrict__ boff,
                                                   int* __restrict__ off,
                                                   int* __restrict__ cursor,
                                                   float* __restrict__ dis) {
  __shared__ int s[256];
  int t = threadIdx.x;
  int i = blockIdx.x * 256 + t;
  int v = counts[i];
  s[t] = v;
  __syncthreads();
  for (int d = 1; d < 256; d <<= 1) {
    int u = (t >= d) ? s[t - d] : 0;
    __syncthreads();
    s[t] += u;
    __syncthreads();
  }
  int ex = boff[blockIdx.x] + s[t] - v;
  off[i] = ex;
  cursor[i] = ex;
  dis[i] = rsqrtf(1.0f + (float)v);
}

// ---------------- scatter edges into CSR (sorted by dst) ------------------
__global__ void k_scatter(const int* __restrict__ src, const int* __restrict__ dst,
                          int* __restrict__ cursor, int* __restrict__ csr_src, int E) {
  int e = blockIdx.x * 256 + threadIdx.x;
  if (e < E) {
    int d = dst[e];
    int p = atomicAdd(&cursor[d], 1);
    csr_src[p] = src[e];
  }
}

// ---------------- transpose weights to bf16 [n][k] ------------------------
__global__ void k_prepw(const float* __restrict__ W1, const float* __restrict__ W2,
                        u16* __restrict__ W1T, u16* __restrict__ W2T) {
  int id = blockIdx.x * 256 + threadIdx.x;
  if (id < F_IN * H_DIM) {
    int k = id >> 8, n = id & 255;
    W1T[n * F_IN + k] = f2bf(W1[id]);
  } else {
    int id2 = id - F_IN * H_DIM;
    if (id2 < H_DIM * H_DIM) {
      int k = id2 >> 8, n = id2 & 255;
      W2T[n * H_DIM + k] = f2bf(W2[id2]);
    }
  }
}

// ---------------- MFMA GEMM: C[M,256] = dis[row] * (A[M,K] @ B[K,256]) ----
// BT is bf16 [256][K] (pre-transposed). Block = 256 thr = 4 waves.
// Tile BM=64 x BN=256 (wave w does cols w*64..w*64+63), BK=32.
// Output rows are pre-scaled by dis[row] so aggregation is a pure gather-sum.
template <bool AF32>
__global__ __launch_bounds__(256) void k_mm(const void* __restrict__ Ap,
                                            const u16* __restrict__ BT,
                                            const float* __restrict__ dis,
                                            u16* __restrict__ C, int M, int K) {
  __shared__ __align__(16) u16 As[64][40];    // +8 pad: 80B row stride, 2-way banks
  __shared__ __align__(16) u16 Bs[256][40];
  int tid = threadIdx.x;
  int lane = tid & 63, wid = tid >> 6;
  int lr = lane & 15, lg = lane >> 4;
  int m0 = blockIdx.x * 64;
  f32x4 acc[4][4] = {};
  int nsteps = (K + 31) >> 5;
  for (int ks = 0; ks < nsteps; ++ks) {
    int k0 = ks << 5;
    // ---- stage A (64x32): each thread 8 elems
    {
      int row = tid >> 2;
      int seg = (tid & 3) << 3;
      int gk = k0 + seg;
      if (AF32) {
        const float* A = (const float*)Ap;
        const float* p = A + (size_t)(m0 + row) * K + gk;
        alignas(16) u16 u[8];
        if (gk + 8 <= K) {
          float4 x0 = *reinterpret_cast<const float4*>(p);
          float4 x1 = *reinterpret_cast<const float4*>(p + 4);
          u[0] = f2bf(x0.x); u[1] = f2bf(x0.y); u[2] = f2bf(x0.z); u[3] = f2bf(x0.w);
          u[4] = f2bf(x1.x); u[5] = f2bf(x1.y); u[6] = f2bf(x1.z); u[7] = f2bf(x1.w);
        } else {
#pragma unroll
          for (int j = 0; j < 8; ++j) u[j] = (gk + j < K) ? f2bf(p[j]) : (u16)0;
        }
        *reinterpret_cast<uint4*>(&As[row][seg]) = *reinterpret_cast<const uint4*>(u);
      } else {
        const u16* A = (const u16*)Ap;
        const u16* p = A + (size_t)(m0 + row) * K + gk;
        if (gk + 8 <= K) {
          *reinterpret_cast<uint4*>(&As[row][seg]) = *reinterpret_cast<const uint4*>(p);
        } else {
          alignas(16) u16 u[8];
#pragma unroll
          for (int j = 0; j < 8; ++j) u[j] = (gk + j < K) ? p[j] : (u16)0;
          *reinterpret_cast<uint4*>(&As[row][seg]) = *reinterpret_cast<const uint4*>(u);
        }
      }
    }
    // ---- stage B (256 n-rows x 32 k): each thread one n row
    {
      int n = tid;
      const u16* p = BT + (size_t)n * K + k0;
      if (k0 + 32 <= K) {
#pragma unroll
        for (int j = 0; j < 4; ++j)
          *reinterpret_cast<uint4*>(&Bs[n][j * 8]) = reinterpret_cast<const uint4*>(p)[j];
      } else {
        alignas(16) u16 u[32];
#pragma unroll
        for (int j = 0; j < 32; ++j) u[j] = (k0 + j < K) ? p[j] : (u16)0;
#pragma unroll
        for (int j = 0; j < 4; ++j)
          *reinterpret_cast<uint4*>(&Bs[n][j * 8]) = reinterpret_cast<const uint4*>(u)[j];
      }
    }
    __syncthreads();
    bf16x8 af[4], bfr[4];
#pragma unroll
    for (int m = 0; m < 4; ++m)
      af[m] = *reinterpret_cast<const bf16x8*>(&As[m * 16 + lr][lg * 8]);
#pragma unroll
    for (int n = 0; n < 4; ++n)
      bfr[n] = *reinterpret_cast<const bf16x8*>(&Bs[wid * 64 + n * 16 + lr][lg * 8]);
#pragma unroll
    for (int m = 0; m < 4; ++m)
#pragma unroll
      for (int n = 0; n < 4; ++n)
        acc[m][n] = __builtin_amdgcn_mfma_f32_16x16x32_bf16(af[m], bfr[n], acc[m][n], 0, 0, 0);
    __syncthreads();
  }
  // ---- epilogue: D[row=(lg*4+r)][col=lr] per 16x16 frag; scale by dis[row]
#pragma unroll
  for (int m = 0; m < 4; ++m)
#pragma unroll
    for (int r = 0; r < 4; ++r) {
      int grow = m0 + m * 16 + lg * 4 + r;
      float ds = dis[grow];
#pragma unroll
      for (int n = 0; n < 4; ++n) {
        int gcol = wid * 64 + n * 16 + lr;
        C[(size_t)grow * H_DIM + gcol] = f2bf(ds * acc[m][n][r]);
      }
    }
}

// ---------------- gather group: U independent row loads, then accumulate --
template <int U>
__device__ __forceinline__ void gath(const u16* __restrict__ t,
                                     const int* __restrict__ csr, int e, int f0,
                                     float& a0, float& a1, float& a2, float& a3) {
  int s[U];
  ushort4 v[U];
#pragma unroll
  for (int i = 0; i < U; ++i) s[i] = csr[e + i];
#pragma unroll
  for (int i = 0; i < U; ++i)
    v[i] = *reinterpret_cast<const ushort4*>(t + ((size_t)s[i] << 8) + f0);
#pragma unroll
  for (int i = 0; i < U; ++i) {
    a0 += bf2f(v[i].x); a1 += bf2f(v[i].y); a2 += bf2f(v[i].z); a3 += bf2f(v[i].w);
  }
}

// ------- aggregation on pre-scaled rows: h[d] = relu(dd*(sum t'[s] + t'[d]) + b)
// one wave per node, lane = 4 features
template <bool RELU>
__global__ __launch_bounds__(256) void k_agg(const u16* __restrict__ t,
                                             const int* __restrict__ off,
                                             const int* __restrict__ csr,
                                             const float* __restrict__ dis,
                                             const float* __restrict__ bias,
                                             u16* __restrict__ h, int N) {
  int wid = threadIdx.x >> 6, lane = threadIdx.x & 63;
  int d = blockIdx.x * 4 + wid;
  if (d >= N) return;
  int f0 = lane * 4;
  float a0, a1, a2, a3;
  {
    ushort4 v = *reinterpret_cast<const ushort4*>(t + ((size_t)d << 8) + f0);
    a0 = bf2f(v.x); a1 = bf2f(v.y); a2 = bf2f(v.z); a3 = bf2f(v.w);
  }
  int e = off[d], e1 = off[d + 1];
  while (e + 8 <= e1) { gath<8>(t, csr, e, f0, a0, a1, a2, a3); e += 8; }
  if (e + 4 <= e1) { gath<4>(t, csr, e, f0, a0, a1, a2, a3); e += 4; }
  if (e + 2 <= e1) { gath<2>(t, csr, e, f0, a0, a1, a2, a3); e += 2; }
  if (e < e1)      { gath<1>(t, csr, e, f0, a0, a1, a2, a3); }
  float dd = dis[d];
  float4 bv = *reinterpret_cast<const float4*>(bias + f0);
  float r0 = dd * a0 + bv.x, r1 = dd * a1 + bv.y;
  float r2 = dd * a2 + bv.z, r3 = dd * a3 + bv.w;
  if (RELU) {
    r0 = fmaxf(r0, 0.f); r1 = fmaxf(r1, 0.f); r2 = fmaxf(r2, 0.f); r3 = fmaxf(r3, 0.f);
  }
  ushort4 o;
  o.x = f2bf(r0); o.y = f2bf(r1); o.z = f2bf(r2); o.w = f2bf(r3);
  *reinterpret_cast<ushort4*>(h + ((size_t)d << 8) + f0) = o;
}

// ---------------- layer 3 matmul: t3'[d] = dis[d] * (h2[d] @ W3) ----------
__global__ __launch_bounds__(256) void k_mm3(const u16* __restrict__ h2,
                                             const float* __restrict__ W3,
                                             const float* __restrict__ dis,
                                             float* __restrict__ t3, int N) {
  int wid = threadIdx.x >> 6, lane = threadIdx.x & 63;
  int d = blockIdx.x * 4 + wid;
  if (d >= N) return;
  int f0 = lane * 4;
  ushort4 v = *reinterpret_cast<const ushort4*>(h2 + ((size_t)d << 8) + f0);
  float a0 = 0.f, a1 = 0.f, f;
  f = bf2f(v.x); a0 += f * W3[(f0 + 0) * 2]; a1 += f * W3[(f0 + 0) * 2 + 1];
  f = bf2f(v.y); a0 += f * W3[(f0 + 1) * 2]; a1 += f * W3[(f0 + 1) * 2 + 1];
  f = bf2f(v.z); a0 += f * W3[(f0 + 2) * 2]; a1 += f * W3[(f0 + 2) * 2 + 1];
  f = bf2f(v.w); a0 += f * W3[(f0 + 3) * 2]; a1 += f * W3[(f0 + 3) * 2 + 1];
#pragma unroll
  for (int o = 32; o; o >>= 1) { a0 += __shfl_xor(a0, o); a1 += __shfl_xor(a1, o); }
  if (lane == 0) {
    float s = dis[d];
    t3[d * 2] = s * a0;
    t3[d * 2 + 1] = s * a1;
  }
}

// ---------------- layer 3 aggregation (2 features, no relu) ---------------
__global__ void k_agg3(const float* __restrict__ t3, const int* __restrict__ off,
                       const int* __restrict__ csr, const float* __restrict__ dis,
                       const float* __restrict__ b3, float* __restrict__ h3, int N) {
  int d = blockIdx.x * 256 + threadIdx.x;
  if (d >= N) return;
  float a0 = t3[d * 2], a1 = t3[d * 2 + 1];
  int e = off[d], e1 = off[d + 1];
  while (e + 4 <= e1) {
    int s0 = csr[e], s1 = csr[e + 1], s2 = csr[e + 2], s3 = csr[e + 3];
    float2 v0 = *reinterpret_cast<const float2*>(t3 + s0 * 2);
    float2 v1 = *reinterpret_cast<const float2*>(t3 + s1 * 2);
    float2 v2 = *reinterpret_cast<const float2*>(t3 + s2 * 2);
    float2 v3 = *reinterpret_cast<const float2*>(t3 + s3 * 2);
    a0 += v0.x + v1.x + v2.x + v3.x;
    a1 += v0.y + v1.y + v2.y + v3.y;
    e += 4;
  }
  while (e < e1) {
    float2 v = *reinterpret_cast<const float2*>(t3 + csr[e] * 2);
    a0 += v.x; a1 += v.y; ++e;
  }
  float dd = dis[d];
  h3[d * 2] = dd * a0 + b3[0];
  h3[d * 2 + 1] = dd * a1 + b3[1];
}

// ---------------- mean pool over 400 nodes per graph ----------------------
__global__ __launch_bounds__(256) void k_pool(const float* __restrict__ h3,
                                              float* __restrict__ out, int G) {
  int wid = threadIdx.x >> 6, lane = threadIdx.x & 63;
  int g = blockIdx.x * 4 + wid;
  if (g >= G) return;
  float a0 = 0.f, a1 = 0.f;
  for (int i = lane; i < NODES_PER_GRAPH; i += 64) {
    int n = g * NODES_PER_GRAPH + i;
    a0 += h3[n * 2]; a1 += h3[n * 2 + 1];
  }
#pragma unroll
  for (int o = 32; o; o >>= 1) { a0 += __shfl_xor(a0, o); a1 += __shfl_xor(a1, o); }
  if (lane == 0) {
    out[g * 2] = a0 * (1.0f / NODES_PER_GRAPH);
    out[g * 2 + 1] = a1 * (1.0f / NODES_PER_GRAPH);
  }
}

extern "C" void kernel_launch(void* const* d_in, const int* in_sizes, int n_in,
                              void* d_out, int out_size, void* d_ws, size_t ws_size,
                              hipStream_t stream) {
  const float* x  = (const float*)d_in[0];
  const int*   ei = (const int*)d_in[1];
  const float* W1 = (const float*)d_in[2];
  const float* b1 = (const float*)d_in[3];
  const float* W2 = (const float*)d_in[4];
  const float* b2 = (const float*)d_in[5];
  const float* W3 = (const float*)d_in[6];
  const float* b3 = (const float*)d_in[7];
  float* out = (float*)d_out;
  const int N = N_NODES, E = N_EDGES;
  const int* src = ei;
  const int* dst = ei + E;

  char* ws = (char*)d_ws;
  size_t o = 0;
  auto alloc = [&](size_t bytes) -> void* {
    void* p = ws + o;
    o += (bytes + 255) & ~(size_t)255;
    return p;
  };
  u16* tA     = (u16*)alloc((size_t)N * H_DIM * 2);
  u16* tB     = (u16*)alloc((size_t)N * H_DIM * 2);
  u16* W1T    = (u16*)alloc((size_t)H_DIM * F_IN * 2);
  u16* W2T    = (u16*)alloc((size_t)H_DIM * H_DIM * 2);
  float* dis  = (float*)alloc((size_t)N * 4);
  int* counts = (int*)alloc((size_t)N * 4);
  int* cursor = (int*)alloc((size_t)N * 4);
  int* csroff = (int*)alloc((size_t)(N + 1) * 4);
  int* csr    = (int*)alloc((size_t)E * 4);
  float* t3   = (float*)alloc((size_t)N * 2 * 4);
  float* h3   = (float*)alloc((size_t)N * 2 * 4);
  int* bsum   = (int*)alloc((size_t)NB_SCAN * 4);
  int* boff   = (int*)alloc((size_t)NB_SCAN * 4);

  hipMemsetAsync(counts, 0, (size_t)N * 4, stream);
  k_hist<<<(E + 255) / 256, 256, 0, stream>>>(dst, counts, E);
  k_reduce<<<NB_SCAN, 256, 0, stream>>>(counts, bsum);
  k_scantop<<<1, 256, 0, stream>>>(bsum, boff, csroff + N);
  k_scanlocal<<<NB_SCAN, 256, 0, stream>>>(counts, boff, csroff, cursor, dis);
  k_scatter<<<(E + 255) / 256, 256, 0, stream>>>(src, dst, cursor, csr, E);
  k_prepw<<<(F_IN * H_DIM + H_DIM * H_DIM + 255) / 256, 256, 0, stream>>>(W1, W2, W1T, W2T);

  // layer 1
  k_mm<true><<<N / 64, 256, 0, stream>>>(x, W1T, dis, tA, N, F_IN);
  k_agg<true><<<N / 4, 256, 0, stream>>>(tA, csroff, csr, dis, b1, tB, N);
  // layer 2
  k_mm<false><<<N / 64, 256, 0, stream>>>(tB, W2T, dis, tA, N, H_DIM);
  k_agg<true><<<N / 4, 256, 0, stream>>>(tA, csroff, csr, dis, b2, tB, N);
  // layer 3
  k_mm3<<<N / 4, 256, 0, stream>>>(tB, W3, dis, t3, N);
  k_agg3<<<(N + 255) / 256, 256, 0, stream>>>(t3, csroff, csr, dis, b3, h3, N);
  k_pool<<<(N_GRAPHS + 3) / 4, 256, 0, stream>>>(h3, out, N_GRAPHS);
}

// Round 4
// 299.454 us; speedup vs baseline: 1.6496x; 1.0869x over previous
//
#include <hip/hip_runtime.h>
#include <hip/hip_bf16.h>
#include <stdint.h>

typedef __attribute__((ext_vector_type(8))) __bf16 bf16x8;
typedef __attribute__((ext_vector_type(4))) float f32x4;
typedef unsigned short u16;

#define N_NODES 51200
#define N_EDGES 819200
#define F_IN 400
#define K1PAD 416
#define H_DIM 256
#define C_OUT 2
#define N_GRAPHS 128
#define NODES_PER_GRAPH 400
#define NB_SCAN (N_NODES / 256)   // 200 blocks

__device__ __forceinline__ u16 f2bf(float f) {
  uint32_t u = __builtin_bit_cast(uint32_t, f);
  u = (u + 0x7fffu + ((u >> 16) & 1u)) >> 16;
  return (u16)u;
}
__device__ __forceinline__ float bf2f(u16 s) {
  uint32_t u = ((uint32_t)s) << 16;
  return __builtin_bit_cast(float, u);
}

typedef const __attribute__((address_space(1))) unsigned int* gas_ptr;
typedef __attribute__((address_space(3))) unsigned int* las_ptr;
__device__ __forceinline__ void gl_lds16(const void* g, void* l) {
  __builtin_amdgcn_global_load_lds((gas_ptr)g, (las_ptr)l, 16, 0, 0);
}

// ---------------- degree histogram (counts[d] = in-degree) ----------------
__global__ void k_hist(const int* __restrict__ dst, int* __restrict__ counts, int E) {
  int e = blockIdx.x * 256 + threadIdx.x;
  if (e < E) atomicAdd(&counts[dst[e]], 1);
}

// ---------------- hierarchical scan: phase 1, per-block sums --------------
__global__ __launch_bounds__(256) void k_reduce(const int* __restrict__ counts,
                                                int* __restrict__ bsum) {
  int i = blockIdx.x * 256 + threadIdx.x;
  int v = counts[i];
#pragma unroll
  for (int o = 32; o; o >>= 1) v += __shfl_xor(v, o);
  __shared__ int wsum[4];
  if ((threadIdx.x & 63) == 0) wsum[threadIdx.x >> 6] = v;
  __syncthreads();
  if (threadIdx.x == 0) bsum[blockIdx.x] = wsum[0] + wsum[1] + wsum[2] + wsum[3];
}

// ---------------- phase 2: scan the 200 block sums (one small block) ------
__global__ __launch_bounds__(256) void k_scantop(const int* __restrict__ bsum,
                                                 int* __restrict__ boff,
                                                 int* __restrict__ off_last) {
  __shared__ int s[256];
  int t = threadIdx.x;
  int v = (t < NB_SCAN) ? bsum[t] : 0;
  s[t] = v;
  __syncthreads();
  for (int d = 1; d < 256; d <<= 1) {
    int u = (t >= d) ? s[t - d] : 0;
    __syncthreads();
    s[t] += u;
    __syncthreads();
  }
  if (t < NB_SCAN) boff[t] = s[t] - v;   // exclusive prefix of block sums
  if (t == 0) *off_last = N_EDGES;       // off[N] = total edges
}

// ---------------- phase 3: local scan + block offset; also dis ------------
__global__ __launch_bounds__(256) void k_scanlocal(const int* __restrict__ counts,
                                                   const int* __restrict__ boff,
                                                   int* __restrict__ off,
                                                   int* __restrict__ cursor,
                                                   float* __restrict__ dis) {
  __shared__ int s[256];
  int t = threadIdx.x;
  int i = blockIdx.x * 256 + t;
  int v = counts[i];
  s[t] = v;
  __syncthreads();
  for (int d = 1; d < 256; d <<= 1) {
    int u = (t >= d) ? s[t - d] : 0;
    __syncthreads();
    s[t] += u;
    __syncthreads();
  }
  int ex = boff[blockIdx.x] + s[t] - v;
  off[i] = ex;
  cursor[i] = ex;
  dis[i] = rsqrtf(1.0f + (float)v);
}

// ---------------- scatter edges into CSR (sorted by dst) ------------------
__global__ void k_scatter(const int* __restrict__ src, const int* __restrict__ dst,
                          int* __restrict__ cursor, int* __restrict__ csr_src, int E) {
  int e = blockIdx.x * 256 + threadIdx.x;
  if (e < E) {
    int d = dst[e];
    int p = atomicAdd(&cursor[d], 1);
    csr_src[p] = src[e];
  }
}

// ------- transpose weights to bf16 [n][k], K1 padded to 416 with zeros ----
// grid = K1PAD + H_DIM blocks, 256 threads: one k-column per block
__global__ __launch_bounds__(256) void k_prepw(const float* __restrict__ W1,
                                               const float* __restrict__ W2,
                                               u16* __restrict__ W1T,
                                               u16* __restrict__ W2T) {
  int b = blockIdx.x, n = threadIdx.x;
  if (b < K1PAD) {
    int k = b;
    W1T[n * K1PAD + k] = (k < F_IN) ? f2bf(W1[k * H_DIM + n]) : (u16)0;
  } else {
    int k = b - K1PAD;
    W2T[n * H_DIM + k] = f2bf(W2[k * H_DIM + n]);
  }
}

// ---------------- MFMA GEMM: C[M,256] = dis[row] * (A[M,K] @ B[K,256]) ----
// BT bf16 [256][KB] (pre-transposed, K padded to KB). 256 thr = 4 waves.
// Tile BM=64 x BN=256; wave w does cols w*64..w*64+63; BK=32.
// Staging: global_load_lds 16B (B always; A when bf16). fp32 A reg-staged
// with load-early/convert-late split so HBM latency hides under MFMA.
template <bool AF32>
__global__ __launch_bounds__(256) void k_mm(const void* __restrict__ Ap,
                                            const u16* __restrict__ BT,
                                            const float* __restrict__ dis,
                                            u16* __restrict__ C, int K, int KB) {
  __shared__ __align__(16) u16 As[64 * 32];
  __shared__ __align__(16) u16 Bs[256 * 32];
  int tid = threadIdx.x;
  int lane = tid & 63, wid = tid >> 6;
  int lr = lane & 15, lg = lane >> 4;
  int m0 = blockIdx.x * 64;
  int nsteps = KB >> 5;

  // B: 4 chunks/thread; chunk group (wid*4+j): rows (wid*4+j)*16+(lane>>2)
  int bRow = (lane >> 2);
  int bK8 = (lane & 3) << 3;
  // A: 1 chunk/thread
  int aRow = tid >> 2;
  int aK8 = (tid & 3) << 3;

  float4 fa0, fa1;   // pending fp32 A loads (AF32 path)

  auto issueB = [&](int k0) {
#pragma unroll
    for (int j = 0; j < 4; ++j) {
      const u16* g = BT + (size_t)((wid * 4 + j) * 16 + bRow) * KB + k0 + bK8;
      gl_lds16(g, (char*)Bs + (wid * 4 + j) * 1024);
    }
  };
  auto issueA16 = [&](int k0) {
    const u16* A = (const u16*)Ap;
    const u16* g = A + (size_t)(m0 + aRow) * KB + k0 + aK8;
    gl_lds16(g, (char*)As + wid * 1024);
  };
  auto loadA32 = [&](int k0) {
    int gk = k0 + aK8;
    const float* A = (const float*)Ap;
    const float* p = A + (size_t)(m0 + aRow) * K + gk;
    if (gk < K) {
      fa0 = *reinterpret_cast<const float4*>(p);
      fa1 = *reinterpret_cast<const float4*>(p + 4);
    } else {
      fa0 = float4{0.f, 0.f, 0.f, 0.f};
      fa1 = float4{0.f, 0.f, 0.f, 0.f};
    }
  };
  auto writeA32 = [&]() {
    alignas(16) u16 u[8];
    u[0] = f2bf(fa0.x); u[1] = f2bf(fa0.y); u[2] = f2bf(fa0.z); u[3] = f2bf(fa0.w);
    u[4] = f2bf(fa1.x); u[5] = f2bf(fa1.y); u[6] = f2bf(fa1.z); u[7] = f2bf(fa1.w);
    *reinterpret_cast<uint4*>(&As[(size_t)tid * 8]) = *reinterpret_cast<const uint4*>(u);
  };

  // prologue: stage step 0
  if (AF32) { loadA32(0); } else { issueA16(0); }
  issueB(0);
  if (AF32) { writeA32(); }

  f32x4 acc[4][4] = {};
  for (int ks = 0; ks < nsteps; ++ks) {
    __syncthreads();   // stage ks complete (vmcnt/lgkm drained by syncthreads)
    bf16x8 af[4], bfr[4];
#pragma unroll
    for (int m = 0; m < 4; ++m)
      af[m] = *reinterpret_cast<const bf16x8*>(&As[(m * 16 + lr) * 32 + lg * 8]);
#pragma unroll
    for (int n = 0; n < 4; ++n)
      bfr[n] = *reinterpret_cast<const bf16x8*>(&Bs[(wid * 64 + n * 16 + lr) * 32 + lg * 8]);
    __syncthreads();   // all frag reads done; safe to overwrite LDS
    bool more = (ks + 1 < nsteps);
    if (more) {
      int k0n = (ks + 1) << 5;
      if (AF32) loadA32(k0n); else issueA16(k0n);
      issueB(k0n);     // async loads fly during the MFMA cluster below
    }
#pragma unroll
    for (int m = 0; m < 4; ++m)
#pragma unroll
      for (int n = 0; n < 4; ++n)
        acc[m][n] = __builtin_amdgcn_mfma_f32_16x16x32_bf16(af[m], bfr[n], acc[m][n], 0, 0, 0);
    if (more && AF32) writeA32();   // convert+ds_write after MFMA (T14 split)
  }

  // ---- epilogue: D[row=(lg*4+r)][col=lr] per 16x16 frag; scale by dis[row]
#pragma unroll
  for (int m = 0; m < 4; ++m)
#pragma unroll
    for (int r = 0; r < 4; ++r) {
      int grow = m0 + m * 16 + lg * 4 + r;
      float ds = dis[grow];
#pragma unroll
      for (int n = 0; n < 4; ++n) {
        int gcol = wid * 64 + n * 16 + lr;
        C[(size_t)grow * H_DIM + gcol] = f2bf(ds * acc[m][n][r]);
      }
    }
}

// ---------------- gather group: U independent row loads, then accumulate --
template <int U>
__device__ __forceinline__ void gath(const u16* __restrict__ t,
                                     const int* __restrict__ csr, int e, int f0,
                                     float& a0, float& a1, float& a2, float& a3) {
  int s[U];
  ushort4 v[U];
#pragma unroll
  for (int i = 0; i < U; ++i) s[i] = csr[e + i];
#pragma unroll
  for (int i = 0; i < U; ++i)
    v[i] = *reinterpret_cast<const ushort4*>(t + ((size_t)s[i] << 8) + f0);
#pragma unroll
  for (int i = 0; i < U; ++i) {
    a0 += bf2f(v[i].x); a1 += bf2f(v[i].y); a2 += bf2f(v[i].z); a3 += bf2f(v[i].w);
  }
}

// ------- aggregation on pre-scaled rows: h[d] = relu(dd*(sum t'[s] + t'[d]) + b)
// one wave per node, lane = 4 features
template <bool RELU>
__global__ __launch_bounds__(256) void k_agg(const u16* __restrict__ t,
                                             const int* __restrict__ off,
                                             const int* __restrict__ csr,
                                             const float* __restrict__ dis,
                                             const float* __restrict__ bias,
                                             u16* __restrict__ h, int N) {
  int wid = threadIdx.x >> 6, lane = threadIdx.x & 63;
  int d = blockIdx.x * 4 + wid;
  if (d >= N) return;
  int f0 = lane * 4;
  float a0, a1, a2, a3;
  {
    ushort4 v = *reinterpret_cast<const ushort4*>(t + ((size_t)d << 8) + f0);
    a0 = bf2f(v.x); a1 = bf2f(v.y); a2 = bf2f(v.z); a3 = bf2f(v.w);
  }
  int e = off[d], e1 = off[d + 1];
  while (e + 8 <= e1) { gath<8>(t, csr, e, f0, a0, a1, a2, a3); e += 8; }
  if (e + 4 <= e1) { gath<4>(t, csr, e, f0, a0, a1, a2, a3); e += 4; }
  if (e + 2 <= e1) { gath<2>(t, csr, e, f0, a0, a1, a2, a3); e += 2; }
  if (e < e1)      { gath<1>(t, csr, e, f0, a0, a1, a2, a3); }
  float dd = dis[d];
  float4 bv = *reinterpret_cast<const float4*>(bias + f0);
  float r0 = dd * a0 + bv.x, r1 = dd * a1 + bv.y;
  float r2 = dd * a2 + bv.z, r3 = dd * a3 + bv.w;
  if (RELU) {
    r0 = fmaxf(r0, 0.f); r1 = fmaxf(r1, 0.f); r2 = fmaxf(r2, 0.f); r3 = fmaxf(r3, 0.f);
  }
  ushort4 o;
  o.x = f2bf(r0); o.y = f2bf(r1); o.z = f2bf(r2); o.w = f2bf(r3);
  *reinterpret_cast<ushort4*>(h + ((size_t)d << 8) + f0) = o;
}

// ---------------- layer 3 matmul: t3'[d] = dis[d] * (h2[d] @ W3) ----------
__global__ __launch_bounds__(256) void k_mm3(const u16* __restrict__ h2,
                                             const float* __restrict__ W3,
                                             const float* __restrict__ dis,
                                             float* __restrict__ t3, int N) {
  int wid = threadIdx.x >> 6, lane = threadIdx.x & 63;
  int d = blockIdx.x * 4 + wid;
  if (d >= N) return;
  int f0 = lane * 4;
  ushort4 v = *reinterpret_cast<const ushort4*>(h2 + ((size_t)d << 8) + f0);
  float a0 = 0.f, a1 = 0.f, f;
  f = bf2f(v.x); a0 += f * W3[(f0 + 0) * 2]; a1 += f * W3[(f0 + 0) * 2 + 1];
  f = bf2f(v.y); a0 += f * W3[(f0 + 1) * 2]; a1 += f * W3[(f0 + 1) * 2 + 1];
  f = bf2f(v.z); a0 += f * W3[(f0 + 2) * 2]; a1 += f * W3[(f0 + 2) * 2 + 1];
  f = bf2f(v.w); a0 += f * W3[(f0 + 3) * 2]; a1 += f * W3[(f0 + 3) * 2 + 1];
#pragma unroll
  for (int o = 32; o; o >>= 1) { a0 += __shfl_xor(a0, o); a1 += __shfl_xor(a1, o); }
  if (lane == 0) {
    float s = dis[d];
    t3[d * 2] = s * a0;
    t3[d * 2 + 1] = s * a1;
  }
}

// ---------------- layer 3 aggregation (2 features, no relu) ---------------
__global__ void k_agg3(const float* __restrict__ t3, const int* __restrict__ off,
                       const int* __restrict__ csr, const float* __restrict__ dis,
                       const float* __restrict__ b3, float* __restrict__ h3, int N) {
  int d = blockIdx.x * 256 + threadIdx.x;
  if (d >= N) return;
  float a0 = t3[d * 2], a1 = t3[d * 2 + 1];
  int e = off[d], e1 = off[d + 1];
  while (e + 4 <= e1) {
    int s0 = csr[e], s1 = csr[e + 1], s2 = csr[e + 2], s3 = csr[e + 3];
    float2 v0 = *reinterpret_cast<const float2*>(t3 + s0 * 2);
    float2 v1 = *reinterpret_cast<const float2*>(t3 + s1 * 2);
    float2 v2 = *reinterpret_cast<const float2*>(t3 + s2 * 2);
    float2 v3 = *reinterpret_cast<const float2*>(t3 + s3 * 2);
    a0 += v0.x + v1.x + v2.x + v3.x;
    a1 += v0.y + v1.y + v2.y + v3.y;
    e += 4;
  }
  while (e < e1) {
    float2 v = *reinterpret_cast<const float2*>(t3 + csr[e] * 2);
    a0 += v.x; a1 += v.y; ++e;
  }
  float dd = dis[d];
  h3[d * 2] = dd * a0 + b3[0];
  h3[d * 2 + 1] = dd * a1 + b3[1];
}

// ---------------- mean pool over 400 nodes per graph ----------------------
__global__ __launch_bounds__(256) void k_pool(const float* __restrict__ h3,
                                              float* __restrict__ out, int G) {
  int wid = threadIdx.x >> 6, lane = threadIdx.x & 63;
  int g = blockIdx.x * 4 + wid;
  if (g >= G) return;
  float a0 = 0.f, a1 = 0.f;
  for (int i = lane; i < NODES_PER_GRAPH; i += 64) {
    int n = g * NODES_PER_GRAPH + i;
    a0 += h3[n * 2]; a1 += h3[n * 2 + 1];
  }
#pragma unroll
  for (int o = 32; o; o >>= 1) { a0 += __shfl_xor(a0, o); a1 += __shfl_xor(a1, o); }
  if (lane == 0) {
    out[g * 2] = a0 * (1.0f / NODES_PER_GRAPH);
    out[g * 2 + 1] = a1 * (1.0f / NODES_PER_GRAPH);
  }
}

extern "C" void kernel_launch(void* const* d_in, const int* in_sizes, int n_in,
                              void* d_out, int out_size, void* d_ws, size_t ws_size,
                              hipStream_t stream) {
  const float* x  = (const float*)d_in[0];
  const int*   ei = (const int*)d_in[1];
  const float* W1 = (const float*)d_in[2];
  const float* b1 = (const float*)d_in[3];
  const float* W2 = (const float*)d_in[4];
  const float* b2 = (const float*)d_in[5];
  const float* W3 = (const float*)d_in[6];
  const float* b3 = (const float*)d_in[7];
  float* out = (float*)d_out;
  const int N = N_NODES, E = N_EDGES;
  const int* src = ei;
  const int* dst = ei + E;

  char* ws = (char*)d_ws;
  size_t o = 0;
  auto alloc = [&](size_t bytes) -> void* {
    void* p = ws + o;
    o += (bytes + 255) & ~(size_t)255;
    return p;
  };
  u16* tA     = (u16*)alloc((size_t)N * H_DIM * 2);
  u16* tB     = (u16*)alloc((size_t)N * H_DIM * 2);
  u16* W1T    = (u16*)alloc((size_t)H_DIM * K1PAD * 2);
  u16* W2T    = (u16*)alloc((size_t)H_DIM * H_DIM * 2);
  float* dis  = (float*)alloc((size_t)N * 4);
  int* counts = (int*)alloc((size_t)N * 4);
  int* cursor = (int*)alloc((size_t)N * 4);
  int* csroff = (int*)alloc((size_t)(N + 1) * 4);
  int* csr    = (int*)alloc((size_t)E * 4);
  float* t3   = (float*)alloc((size_t)N * 2 * 4);
  float* h3   = (float*)alloc((size_t)N * 2 * 4);
  int* bsum   = (int*)alloc((size_t)NB_SCAN * 4);
  int* boff   = (int*)alloc((size_t)NB_SCAN * 4);

  hipMemsetAsync(counts, 0, (size_t)N * 4, stream);
  k_hist<<<(E + 255) / 256, 256, 0, stream>>>(dst, counts, E);
  k_reduce<<<NB_SCAN, 256, 0, stream>>>(counts, bsum);
  k_scantop<<<1, 256, 0, stream>>>(bsum, boff, csroff + N);
  k_scanlocal<<<NB_SCAN, 256, 0, stream>>>(counts, boff, csroff, cursor, dis);
  k_scatter<<<(E + 255) / 256, 256, 0, stream>>>(src, dst, cursor, csr, E);
  k_prepw<<<K1PAD + H_DIM, 256, 0, stream>>>(W1, W2, W1T, W2T);

  // layer 1
  k_mm<true><<<N / 64, 256, 0, stream>>>(x, W1T, dis, tA, F_IN, K1PAD);
  k_agg<true><<<N / 4, 256, 0, stream>>>(tA, csroff, csr, dis, b1, tB, N);
  // layer 2
  k_mm<false><<<N / 64, 256, 0, stream>>>(tB, W2T, dis, tA, H_DIM, H_DIM);
  k_agg<true><<<N / 4, 256, 0, stream>>>(tA, csroff, csr, dis, b2, tB, N);
  // layer 3
  k_mm3<<<N / 4, 256, 0, stream>>>(tB, W3, dis, t3, N);
  k_agg3<<<(N + 255) / 256, 256, 0, stream>>>(t3, csroff, csr, dis, b3, h3, N);
  k_pool<<<(N_GRAPHS + 3) / 4, 256, 0, stream>>>(h3, out, N_GRAPHS);
}